// Round 9
// baseline (23.655 us; speedup 1.0000x reference)
//
#include <hip/hip_runtime.h>

#define LSTREAM 512
#define C 8
#define OUTD 584    // 8 + 64 + 512
#define NW 16       // waves per block (segments per batch)
#define SEG 32      // steps per wave (wave 15's step 511 is an exact no-op)
#define INCF 4096   // 512 rows x 8 floats (row 511 zeroed)
#define PSTRIDE 600 // partial-signature stride in floats

// Chen combine: state (a, in regs) <- a (x) b (in LDS at bp). a is earlier.
// Lane = i*8+j owns a2[i][j] (s2), a3[i][j][0..7] (s3); s1i = a1[i].
__device__ __forceinline__ void chen_combine(const float* bp, int i, int j, int lane,
                                             float& s1i, float& s2, float (&s3)[C]) {
    const float  b1i  = bp[i];
    const float  b1j  = bp[j];
    const float4 b1lo = *reinterpret_cast<const float4*>(bp);
    const float4 b1hi = *reinterpret_cast<const float4*>(bp + 4);
    const float4 b2lo = *reinterpret_cast<const float4*>(bp + C + j * C);
    const float4 b2hi = *reinterpret_cast<const float4*>(bp + C + j * C + 4);
    const float  b2ij = bp[C + lane];
    const float4 b3lo = *reinterpret_cast<const float4*>(bp + C + 64 + lane * C);
    const float4 b3hi = *reinterpret_cast<const float4*>(bp + C + 64 + lane * C + 4);
    const float b1k[C]  = {b1lo.x, b1lo.y, b1lo.z, b1lo.w, b1hi.x, b1hi.y, b1hi.z, b1hi.w};
    const float b2jk[C] = {b2lo.x, b2lo.y, b2lo.z, b2lo.w, b2hi.x, b2hi.y, b2hi.z, b2hi.w};
    const float b3k[C]  = {b3lo.x, b3lo.y, b3lo.z, b3lo.w, b3hi.x, b3hi.y, b3hi.z, b3hi.w};
    #pragma unroll
    for (int k = 0; k < C; ++k)
        s3[k] = s3[k] + b3k[k] + s1i * b2jk[k] + s2 * b1k[k];
    s2 = s2 + b2ij + s1i * b1j;
    s1i += b1i;
}

__device__ __forceinline__ void store_partial(float* pp, int i, int j, int lane,
                                              float s1i, float s2, const float (&s3)[C]) {
    if (j == 0) pp[i] = s1i;
    pp[C + lane] = s2;
    #pragma unroll
    for (int k = 0; k < C; ++k) pp[C + 64 + lane * C + k] = s3[k];
}

__global__ __launch_bounds__(1024, 8) void sig_kernel(const float* __restrict__ path,
                                                      float* __restrict__ out) {
    __shared__ float inc[INCF];            // 16 KB: increments, row 511 = 0
    __shared__ float part[NW * PSTRIDE];   // 37.5 KB: per-wave partials
    const int b    = blockIdx.x;
    const int tid  = threadIdx.x;
    const int wu   = tid >> 6;
    const int lane = tid & 63;
    const int i = lane >> 3;
    const int j = lane & 7;

    const float* pb = path + (size_t)b * (LSTREAM * C);

    // ---- pre-pass: increments -> LDS (coalesced float4); zero row 511 ----
    // side effect: warms this block's 16 KB path segment into L1 for the
    // broadcast row loads in the main loop.
    {
        const int row = tid >> 1;
        float4 d = {0.f, 0.f, 0.f, 0.f};
        if (row < LSTREAM - 1) {
            const float4* p4 = reinterpret_cast<const float4*>(pb);
            const float4 a = p4[tid];
            const float4 c = p4[tid + 2];
            d.x = c.x - a.x; d.y = c.y - a.y; d.z = c.z - a.z; d.w = c.w - a.w;
        }
        reinterpret_cast<float4*>(inc)[tid] = d;
    }
    __syncthreads();

    const int r0 = wu * SEG;
    const float* pI = inc + r0 * C + i;    // per-lane dxi stream (8-way broadcast, conflict-free)
    const float* pJ = inc + r0 * C + j;
    const float4* xr = reinterpret_cast<const float4*>(pb);  // path rows: row t = xr[2t], xr[2t+1]

    float s1i = 0.f, s2 = 0.f, cfp = 0.f;
    float s3[C];
    #pragma unroll
    for (int k = 0; k < C; ++k) s3[k] = 0.f;

    // row ping-pong in VGPRs via uniform-address (broadcast) VMEM loads:
    // cur = row r0+s, nxt = row r0+s+1; prefetch row r0+s+2 each step.
    float4 c0 = xr[(size_t)(r0) * 2],     c1 = xr[(size_t)(r0) * 2 + 1];
    float4 n0 = xr[(size_t)(r0 + 1) * 2], n1 = xr[(size_t)(r0 + 1) * 2 + 1];

    // summation by parts: s3 = sum_s (cf_{s-1} - cf_s) * x_{r0+s} + cf_last * x_{r0+32}
    #pragma unroll 2
    for (int s = 0; s < SEG; ++s) {
        const int rn = min(r0 + s + 2, LSTREAM - 1);     // clamp only matters for wave 15
        const float4 p0 = xr[(size_t)rn * 2];
        const float4 p1 = xr[(size_t)rn * 2 + 1];

        const float dxi = pI[s * C];
        const float dxj = pJ[s * C];
        const float u  = dxi * dxj;
        const float t1 = s1i * dxj;
        const float cf = fmaf(u, (1.f / 6.f), fmaf(t1, 0.5f, s2));
        const float w  = cfp - cf;
        s3[0] = fmaf(w, c0.x, s3[0]);
        s3[1] = fmaf(w, c0.y, s3[1]);
        s3[2] = fmaf(w, c0.z, s3[2]);
        s3[3] = fmaf(w, c0.w, s3[3]);
        s3[4] = fmaf(w, c1.x, s3[4]);
        s3[5] = fmaf(w, c1.y, s3[5]);
        s3[6] = fmaf(w, c1.z, s3[6]);
        s3[7] = fmaf(w, c1.w, s3[7]);
        s2 = fmaf(u, 0.5f, s2) + t1;
        s1i += dxi;
        cfp = cf;
        c0 = n0; c1 = n1;   // rotate (SSA'd away under unroll)
        n0 = p0; n1 = p1;
    }
    // closing term: cur now = row min(r0+32, 511)
    s3[0] = fmaf(cfp, c0.x, s3[0]);
    s3[1] = fmaf(cfp, c0.y, s3[1]);
    s3[2] = fmaf(cfp, c0.z, s3[2]);
    s3[3] = fmaf(cfp, c0.w, s3[3]);
    s3[4] = fmaf(cfp, c1.x, s3[4]);
    s3[5] = fmaf(cfp, c1.y, s3[5]);
    s3[6] = fmaf(cfp, c1.z, s3[6]);
    s3[7] = fmaf(cfp, c1.w, s3[7]);

    // ---- publish partials, tree-combine 16 -> 1 ----
    store_partial(part + wu * PSTRIDE, i, j, lane, s1i, s2, s3);
    __syncthreads();

    if ((wu & 1) == 0) chen_combine(part + (wu + 1) * PSTRIDE, i, j, lane, s1i, s2, s3);
    if (wu == 2 || wu == 6 || wu == 10 || wu == 14)
        store_partial(part + wu * PSTRIDE, i, j, lane, s1i, s2, s3);
    __syncthreads();

    if ((wu & 3) == 0) chen_combine(part + (wu + 2) * PSTRIDE, i, j, lane, s1i, s2, s3);
    if (wu == 4 || wu == 12)
        store_partial(part + wu * PSTRIDE, i, j, lane, s1i, s2, s3);
    __syncthreads();

    if ((wu & 7) == 0) chen_combine(part + (wu + 4) * PSTRIDE, i, j, lane, s1i, s2, s3);
    if (wu == 8)
        store_partial(part + wu * PSTRIDE, i, j, lane, s1i, s2, s3);
    __syncthreads();

    if (wu == 0) {
        chen_combine(part + 8 * PSTRIDE, i, j, lane, s1i, s2, s3);
        float* ob = out + (size_t)b * OUTD;
        const float s1out = __shfl(s1i, (lane << 3) & 63, 64);
        if (lane < C) ob[lane] = s1out;
        ob[C + lane] = s2;
        #pragma unroll
        for (int k = 0; k < C; ++k) ob[C + 64 + lane * C + k] = s3[k];
    }
}

extern "C" void kernel_launch(void* const* d_in, const int* in_sizes, int n_in,
                              void* d_out, int out_size, void* d_ws, size_t ws_size,
                              hipStream_t stream) {
    const float* path = (const float*)d_in[0];
    float* out = (float*)d_out;
    const int B = in_sizes[0] / (LSTREAM * C);
    sig_kernel<<<B, 1024, 0, stream>>>(path, out);
}